// Round 3
// baseline (911.594 us; speedup 1.0000x reference)
//
#include <hip/hip_runtime.h>
#include <hip/hip_bf16.h>
#include <cstdint>
#include <cmath>

#define BB 1024
#define CC 256
#define SS 64
#define DD 128
#define TOPKN 8
#define EPSF 1e-8f

// ---------------- kernel 0: n_emb[b] = ||emb[b]|| ----------------
__global__ __launch_bounds__(256) void nemb_kernel(const float* __restrict__ emb,
                                                   float* __restrict__ nemb) {
    int b = blockIdx.x * 4 + (threadIdx.x >> 6);
    int l = threadIdx.x & 63;
    const float* e = emb + (size_t)b * DD;
    float x0 = e[l], x1 = e[64 + l];
    float s = x0 * x0 + x1 * x1;
    #pragma unroll
    for (int off = 32; off; off >>= 1) s += __shfl_down(s, off);
    if (l == 0) nemb[b] = sqrtf(s);
}

// ------- kernel 1: Gram G[c] = W[c] W[c]^T (64x64), invnw = 1/sqrt(diag) -------
__global__ __launch_bounds__(256) void gram_kernel(const float* __restrict__ weight,
                                                   float* __restrict__ G,
                                                   float* __restrict__ invnw_g) {
    __shared__ float Wc[SS][DD + 4];
    int c = blockIdx.x;
    const float4* wsrc = (const float4*)(weight + (size_t)c * SS * DD);
    for (int i = threadIdx.x; i < SS * DD / 4; i += 256) {
        int s = i >> 5, d4 = i & 31;
        *(float4*)&Wc[s][d4 << 2] = wsrc[i];
    }
    __syncthreads();
    int ti = threadIdx.x >> 4, tj = threadIdx.x & 15;
    float acc[4][4] = {};
    for (int d = 0; d < DD; d += 4) {
        float4 a[4], bv[4];
        #pragma unroll
        for (int r = 0; r < 4; r++) a[r] = *(const float4*)&Wc[4 * ti + r][d];
        #pragma unroll
        for (int r = 0; r < 4; r++) bv[r] = *(const float4*)&Wc[4 * tj + r][d];
        #pragma unroll
        for (int r = 0; r < 4; r++)
            #pragma unroll
            for (int q = 0; q < 4; q++)
                acc[r][q] += a[r].x * bv[q].x + a[r].y * bv[q].y +
                             a[r].z * bv[q].z + a[r].w * bv[q].w;
    }
    float* Gc = G + (size_t)c * SS * SS;
    #pragma unroll
    for (int r = 0; r < 4; r++)
        #pragma unroll
        for (int q = 0; q < 4; q++) {
            int s1 = 4 * ti + r, s2 = 4 * tj + q;
            Gc[s1 * SS + s2] = acc[r][q];
            if (s1 == s2) invnw_g[c * SS + s1] = 1.0f / sqrtf(fmaxf(acc[r][q], 1e-30f));
        }
}

// ---------------- kernel 2: dot[c][b][s] = emb[b] . W[c][s] ----------------
// block = (bgroup of 64, c). Wave wu covers s in [16wu, 16wu+16). W-row address is
// readfirstlane-uniform -> s_load -> SGPR-broadcast FMA operand (no replication).
__global__ __launch_bounds__(256) void dot_kernel(const float* __restrict__ emb,
                                                  const float* __restrict__ weight,
                                                  float* __restrict__ dot) {
    __shared__ float dotL[SS][SS + 2];   // [s][b], stride 66: 2-way = free
    int tid = threadIdx.x, lane = tid & 63;
    int b0 = blockIdx.x * 64, c = blockIdx.y;
    int wu = __builtin_amdgcn_readfirstlane(tid >> 6);   // provably wave-uniform

    // emb row in VGPRs (32 float4 = 128 regs)
    const float4* ep = (const float4*)(emb + (size_t)(b0 + lane) * DD);
    float4 e[32];
    #pragma unroll
    for (int i = 0; i < 32; i++) e[i] = ep[i];

    const float* wbase = weight + ((size_t)c * SS + (size_t)wu * 16) * DD;
    for (int si = 0; si < 16; si++) {
        const float4* wr = (const float4*)(wbase + si * DD);   // uniform -> s_load
        float a0 = 0.f, a1 = 0.f, a2 = 0.f, a3 = 0.f;
        #pragma unroll
        for (int i = 0; i < 32; i++) {
            float4 wv = wr[i];                                  // SGPR values
            a0 = fmaf(e[i].x, wv.x, a0);
            a1 = fmaf(e[i].y, wv.y, a1);
            a2 = fmaf(e[i].z, wv.z, a2);
            a3 = fmaf(e[i].w, wv.w, a3);
        }
        dotL[wu * 16 + si][lane] = (a0 + a1) + (a2 + a3);
    }
    __syncthreads();

    // coalesced flush: dot[c][b0+b][s], 4 float4 per thread
    float* dbase = dot + ((size_t)c * BB + b0) * SS;
    #pragma unroll
    for (int j = 0; j < 4; j++) {
        int f = j * 256 + tid;          // float4 index in 64x64 tile
        int bi = f >> 4;
        int s4 = (f & 15) << 2;
        float4 v = make_float4(dotL[s4][bi], dotL[s4 + 1][bi],
                               dotL[s4 + 2][bi], dotL[s4 + 3][bi]);
        ((float4*)dbase)[f] = v;
    }
}

// ---------------- kernel 3: epilogue, one thread per (b,c) ----------------
// block = 256 b's for one c (c = blockIdx.y -> scalar invnw/G bases).
__global__ __launch_bounds__(256) void epi_kernel(const float* __restrict__ dot,
                                                  const float* __restrict__ G,
                                                  const float* __restrict__ invnw_g,
                                                  const float* __restrict__ nemb,
                                                  float* __restrict__ out) {
    __shared__ float Gs[SS * SS];       // 16 KB: kill scattered-global gathers
    int tid = threadIdx.x;
    int c = blockIdx.y;
    int b = blockIdx.x * 256 + tid;

    // stage G[c] (coalesced, 4 float4/thread)
    const float4* gsrc = (const float4*)(G + (size_t)c * SS * SS);
    #pragma unroll
    for (int j = 0; j < 4; j++) {
        float4 v = gsrc[j * 256 + tid];
        *(float4*)&Gs[(j * 256 + tid) * 4] = v;
    }

    const float* inw = invnw_g + c * SS;            // scalar base -> s_loads
    const float4* drow = (const float4*)(dot + ((size_t)c * BB + b) * SS);
    float4 dr[16];
    #pragma unroll
    for (int i = 0; i < 16; i++) dr[i] = drow[i];
    float ne = nemb[b];
    float inv_ne = 1.0f / ne;

    // top-8 by key = dot*invnw (ranking-equivalent: inv_ne>0 is constant over s)
    float ts[TOPKN]; int ti[TOPKN];
    #pragma unroll
    for (int k = 0; k < TOPKN; k++) { ts[k] = -INFINITY; ti[k] = 0; }
    #pragma unroll
    for (int j = 0; j < 16; j++) {
        float kv[4] = { dr[j].x, dr[j].y, dr[j].z, dr[j].w };
        #pragma unroll
        for (int q = 0; q < 4; q++) {
            int s = j * 4 + q;
            float xs = kv[q] * inw[s];
            int xi = s;
            #pragma unroll
            for (int k = 0; k < TOPKN; k++) {
                bool gt = xs > ts[k];                   // strict: ties keep lower s
                float hs = gt ? xs : ts[k];  int hi = gt ? xi : ti[k];
                float ls = gt ? ts[k] : xs;  int li = gt ? ti[k] : xi;
                ts[k] = hs; ti[k] = hi; xs = ls; xi = li;
            }
        }
    }
    __syncthreads();   // Gs ready (placed late: staging overlapped with scan)

    // scores & softmax (cos_k = key_k * inv_ne; 1-2 ulp from ref's div — fine)
    float sc[TOPKN];
    #pragma unroll
    for (int k = 0; k < TOPKN; k++) {
        float cosk = ts[k] * inv_ne;
        sc[k] = (1.0f + cosk) * 0.5f + EPSF;
    }
    float wk[TOPKN], wsum = 0.f;
    #pragma unroll
    for (int k = 0; k < TOPKN; k++) {
        float ev = expf(sc[k] - sc[0]);
        wk[k] = ev; wsum += ev;
    }
    float winv = 1.0f / wsum;

    // dot_k = key_k * nw_k ; nw_k = sqrt(G[idx,idx])
    float Gd[TOPKN];
    #pragma unroll
    for (int k = 0; k < TOPKN; k++) Gd[k] = Gs[ti[k] * SS + ti[k]];
    float dot2 = 0.f;
    #pragma unroll
    for (int k = 0; k < TOPKN; k++) dot2 += wk[k] * ts[k] * sqrtf(Gd[k]);

    float np2 = 0.f;
    #pragma unroll
    for (int j = 0; j < TOPKN; j++) {
        float wj = wk[j];
        np2 += wj * wj * Gd[j];
        #pragma unroll
        for (int k2 = j + 1; k2 < TOPKN; k2++)
            np2 += 2.0f * wj * wk[k2] * Gs[ti[j] * SS + ti[k2]];
    }
    dot2 *= winv;
    np2 *= winv * winv;

    float denom2 = fmaxf(sqrtf(fmaxf(np2, 0.f)) * ne, EPSF);
    float cos2 = dot2 / denom2;
    out[(size_t)b * CC + c] = ((1.0f + cos2) * 0.5f + EPSF) / 0.1f;
}

extern "C" void kernel_launch(void* const* d_in, const int* in_sizes, int n_in,
                              void* d_out, int out_size, void* d_ws, size_t ws_size,
                              hipStream_t stream) {
    const float* emb    = (const float*)d_in[0];
    const float* weight = (const float*)d_in[1];
    float* G     = (float*)d_ws;                       // 4 MB
    float* invnw = G + (size_t)CC * SS * SS;           // 64 KB
    float* nemb  = invnw + (size_t)CC * SS;            // 4 KB
    float* dotws = nemb + BB;                          // 67.1 MB
    float* out   = (float*)d_out;

    hipLaunchKernelGGL(nemb_kernel, dim3(BB / 4), dim3(256), 0, stream, emb, nemb);
    hipLaunchKernelGGL(gram_kernel, dim3(CC), dim3(256), 0, stream, weight, G, invnw);
    hipLaunchKernelGGL(dot_kernel, dim3(BB / 64, CC), dim3(256), 0, stream,
                       emb, weight, dotws);
    hipLaunchKernelGGL(epi_kernel, dim3(BB / 256, CC), dim3(256), 0, stream,
                       dotws, G, invnw, nemb, out);
}

// Round 4
// 122.038 us; speedup vs baseline: 7.4698x; 7.4698x over previous
//
#include <hip/hip_runtime.h>
#include <cstdint>
#include <cmath>

#define BB 1024
#define CC 256
#define SS 64
#define DD 128
#define TOPKN 8
#define EPSF 1e-8f

typedef __attribute__((ext_vector_type(8))) short short8;
typedef __attribute__((ext_vector_type(16))) float f32x16;

static __device__ __forceinline__ unsigned short f2bf(float x) {
    uint32_t u = __float_as_uint(x);
    uint32_t r = (u + 0x7FFFu + ((u >> 16) & 1u)) >> 16;   // RNE
    return (unsigned short)r;
}
static __device__ __forceinline__ float bf2f(unsigned short h) {
    return __uint_as_float(((uint32_t)h) << 16);
}

// ---- kernel 0: split emb -> bf16 hi/lo in A-fragment layout + ||emb|| ----
// A-frag (32x32x16): lane ln holds A[row=ln&31][k=(ln>>5)*8+j], j=0..7.
// Storage: ehi[((m*8+t)*64+ln)*8+j] = bf16(emb[m*32+(ln&31)][t*16+(ln>>5)*8+j])
__global__ __launch_bounds__(256) void semb_kernel(const float* __restrict__ emb,
                                                   unsigned short* __restrict__ ehi,
                                                   unsigned short* __restrict__ elo,
                                                   float* __restrict__ nemb) {
    int gid = blockIdx.x * 256 + threadIdx.x;   // 16384 threads: (b, kgroup8)
    int b = gid >> 4, kg = gid & 15;
    const float4* src = (const float4*)(emb + (size_t)b * DD + kg * 8);
    float4 v0 = src[0], v1 = src[1];
    float x[8] = {v0.x, v0.y, v0.z, v0.w, v1.x, v1.y, v1.z, v1.w};
    short8 h8, l8;
    float ss = 0.f;
    #pragma unroll
    for (int j = 0; j < 8; j++) {
        unsigned short h = f2bf(x[j]);
        float hf = bf2f(h);
        h8[j] = (short)h;
        l8[j] = (short)f2bf(x[j] - hf);        // x-hf exact in fp32
        ss += x[j] * x[j];
    }
    int m = b >> 5, t = kg >> 1, ln = (kg & 1) * 32 + (b & 31);
    size_t o = ((size_t)(m * 8 + t)) * 64 + ln;
    ((short8*)ehi)[o] = h8;
    ((short8*)elo)[o] = l8;
    #pragma unroll
    for (int off = 8; off; off >>= 1) ss += __shfl_down(ss, off);
    if ((threadIdx.x & 15) == 0) nemb[b] = sqrtf(ss);
}

// ---- kernel 1: Gram G[c]=W[c]W[c]^T, invnw=1/sqrt(diag), W bf16 hi/lo frags ----
// B-frag (32x32x16): lane ln holds B[k=(ln>>5)*8+j][col=ln&31] = W[col][k].
__global__ __launch_bounds__(256) void gram_kernel(const float* __restrict__ weight,
                                                   float* __restrict__ G,
                                                   float* __restrict__ invnw_g,
                                                   unsigned short* __restrict__ whi,
                                                   unsigned short* __restrict__ wlo) {
    __shared__ float Wc[SS][DD + 4];
    int c = blockIdx.x, tid = threadIdx.x;
    const float4* wsrc = (const float4*)(weight + (size_t)c * SS * DD);
    for (int i = tid; i < SS * DD / 4; i += 256) {
        int s = i >> 5, d4 = i & 31;
        *(float4*)&Wc[s][d4 << 2] = wsrc[i];
    }
    __syncthreads();

    // emit bf16 hi/lo fragments (1024 groups of 8, 4 per thread)
    for (int g = tid; g < 1024; g += 256) {
        int s = g >> 4, kg = g & 15;
        short8 h8, l8;
        #pragma unroll
        for (int j = 0; j < 8; j++) {
            float x = Wc[s][kg * 8 + j];
            unsigned short h = f2bf(x);
            h8[j] = (short)h;
            l8[j] = (short)f2bf(x - bf2f(h));
        }
        int n = s >> 5, t = kg >> 1, ln = (kg & 1) * 32 + (s & 31);
        size_t o = ((size_t)(c * 2 + n) * 8 + t) * 64 + ln;
        ((short8*)whi)[o] = h8;
        ((short8*)wlo)[o] = l8;
    }

    // Gram 64x64 (fp32 exact path, unchanged from R3 which passed)
    int ti = tid >> 4, tj = tid & 15;
    float acc[4][4] = {};
    for (int d = 0; d < DD; d += 4) {
        float4 a[4], bv[4];
        #pragma unroll
        for (int r = 0; r < 4; r++) a[r] = *(const float4*)&Wc[4 * ti + r][d];
        #pragma unroll
        for (int r = 0; r < 4; r++) bv[r] = *(const float4*)&Wc[4 * tj + r][d];
        #pragma unroll
        for (int r = 0; r < 4; r++)
            #pragma unroll
            for (int q = 0; q < 4; q++)
                acc[r][q] += a[r].x * bv[q].x + a[r].y * bv[q].y +
                             a[r].z * bv[q].z + a[r].w * bv[q].w;
    }
    float* Gc = G + (size_t)c * SS * SS;
    #pragma unroll
    for (int r = 0; r < 4; r++)
        #pragma unroll
        for (int q = 0; q < 4; q++) {
            int s1 = 4 * ti + r, s2 = 4 * tj + q;
            Gc[s1 * SS + s2] = acc[r][q];
            if (s1 == s2) invnw_g[c * SS + s1] = 1.0f / sqrtf(fmaxf(acc[r][q], 1e-30f));
        }
}

// ---- kernel 2: fused MFMA dot (128b x 64s per block, one c) + epilogue ----
__global__ __launch_bounds__(128) void main_kernel(const unsigned short* __restrict__ ehi,
                                                   const unsigned short* __restrict__ elo,
                                                   const unsigned short* __restrict__ whi,
                                                   const unsigned short* __restrict__ wlo,
                                                   const float* __restrict__ G,
                                                   const float* __restrict__ invnw_g,
                                                   const float* __restrict__ nemb,
                                                   float* __restrict__ out) {
    __shared__ float dotL[128][66];     // 33.8 KB; stride 66 -> 2-way conflicts only
    __shared__ float Gs[SS * SS];       // 16 KB
    __shared__ float invnwL[SS];
    int tid = threadIdx.x, lane = tid & 63, w = tid >> 6;
    int c = blockIdx.y, b0 = blockIdx.x * 128;

    // ---------------- GEMM phase: bf16x3 split MFMA ----------------
    const short8* Ah = (const short8*)ehi;
    const short8* Al = (const short8*)elo;
    const short8* Bh = (const short8*)whi;
    const short8* Bl = (const short8*)wlo;
    int mbase = blockIdx.x * 4 + w * 2;          // global m-tile for mi=0
    f32x16 acc[2][2] = {};
    #pragma unroll
    for (int t = 0; t < 8; t++) {
        short8 a_h[2], a_l[2], b_h[2], b_l[2];
        #pragma unroll
        for (int mi = 0; mi < 2; mi++) {
            size_t o = ((size_t)(mbase + mi) * 8 + t) * 64 + lane;
            a_h[mi] = Ah[o]; a_l[mi] = Al[o];
        }
        #pragma unroll
        for (int ni = 0; ni < 2; ni++) {
            size_t o = ((size_t)(c * 2 + ni) * 8 + t) * 64 + lane;
            b_h[ni] = Bh[o]; b_l[ni] = Bl[o];
        }
        #pragma unroll
        for (int mi = 0; mi < 2; mi++)
            #pragma unroll
            for (int ni = 0; ni < 2; ni++) {
                acc[mi][ni] = __builtin_amdgcn_mfma_f32_32x32x16_bf16(a_h[mi], b_h[ni], acc[mi][ni], 0, 0, 0);
                acc[mi][ni] = __builtin_amdgcn_mfma_f32_32x32x16_bf16(a_h[mi], b_l[ni], acc[mi][ni], 0, 0, 0);
                acc[mi][ni] = __builtin_amdgcn_mfma_f32_32x32x16_bf16(a_l[mi], b_h[ni], acc[mi][ni], 0, 0, 0);
            }
    }
    // C/D layout (measured m74/m101): col=lane&31, row=(r&3)+8*(r>>2)+4*(lane>>5)
    #pragma unroll
    for (int mi = 0; mi < 2; mi++)
        #pragma unroll
        for (int ni = 0; ni < 2; ni++)
            #pragma unroll
            for (int r = 0; r < 16; r++) {
                int row = (r & 3) + 8 * (r >> 2) + 4 * (lane >> 5);
                dotL[w * 64 + mi * 32 + row][ni * 32 + (lane & 31)] = acc[mi][ni][r];
            }

    // stage G[c] + invnw[c] (coalesced)
    const float4* gsrc = (const float4*)(G + (size_t)c * SS * SS);
    #pragma unroll
    for (int j = 0; j < 8; j++)
        ((float4*)Gs)[j * 128 + tid] = gsrc[j * 128 + tid];
    if (tid < SS) invnwL[tid] = invnw_g[c * SS + tid];
    __syncthreads();

    // ---------------- epilogue: 1 thread per b ----------------
    int b = b0 + tid;
    float ne = nemb[b];
    float inv_ne = 1.0f / ne;

    float ts[TOPKN]; int ti8[TOPKN];
    #pragma unroll
    for (int k = 0; k < TOPKN; k++) { ts[k] = -INFINITY; ti8[k] = 0; }
    #pragma unroll 4
    for (int s = 0; s < SS; s++) {
        float xs = dotL[tid][s] * invnwL[s];   // key: positive scale of cos
        int xi = s;
        #pragma unroll
        for (int k = 0; k < TOPKN; k++) {
            bool gt = xs > ts[k];              // strict: ties keep lower s
            float hs = gt ? xs : ts[k];  int hi = gt ? xi : ti8[k];
            float ls = gt ? ts[k] : xs;  int li = gt ? ti8[k] : xi;
            ts[k] = hs; ti8[k] = hi; xs = ls; xi = li;
        }
    }
    // softmax over scores (ts[0] max)
    float sc[TOPKN];
    #pragma unroll
    for (int k = 0; k < TOPKN; k++) {
        float cosk = ts[k] * inv_ne;
        sc[k] = (1.0f + cosk) * 0.5f + EPSF;
    }
    float wk[TOPKN], wsum = 0.f;
    #pragma unroll
    for (int k = 0; k < TOPKN; k++) {
        float ev = expf(sc[k] - sc[0]);
        wk[k] = ev; wsum += ev;
    }
    float winv = 1.0f / wsum;

    float dot2 = 0.f;
    #pragma unroll
    for (int k = 0; k < TOPKN; k++) dot2 += wk[k] * dotL[tid][ti8[k]];

    float np2 = 0.f;
    #pragma unroll
    for (int j = 0; j < TOPKN; j++) {
        float wj = wk[j];
        np2 += wj * wj * Gs[ti8[j] * SS + ti8[j]];
        #pragma unroll
        for (int k2 = j + 1; k2 < TOPKN; k2++)
            np2 += 2.0f * wj * wk[k2] * Gs[ti8[j] * SS + ti8[k2]];
    }
    dot2 *= winv;
    np2 *= winv * winv;

    float denom2 = fmaxf(sqrtf(fmaxf(np2, 0.f)) * ne, EPSF);
    float cos2 = dot2 / denom2;
    out[(size_t)b * CC + c] = ((1.0f + cos2) * 0.5f + EPSF) / 0.1f;
}

extern "C" void kernel_launch(void* const* d_in, const int* in_sizes, int n_in,
                              void* d_out, int out_size, void* d_ws, size_t ws_size,
                              hipStream_t stream) {
    const float* emb    = (const float*)d_in[0];
    const float* weight = (const float*)d_in[1];
    float* G     = (float*)d_ws;                                  // 4 MB
    float* invnw = G + (size_t)CC * SS * SS;                      // 64 KB
    float* nemb  = invnw + CC * SS;                               // 4 KB
    unsigned short* ehi = (unsigned short*)(nemb + BB);           // 256 KB
    unsigned short* elo = ehi + (size_t)BB * DD;                  // 256 KB
    unsigned short* whi = elo + (size_t)BB * DD;                  // 4 MB
    unsigned short* wlo = whi + (size_t)CC * SS * DD;             // 4 MB
    float* out = (float*)d_out;

    hipLaunchKernelGGL(semb_kernel, dim3(BB * 16 / 256), dim3(256), 0, stream,
                       emb, ehi, elo, nemb);
    hipLaunchKernelGGL(gram_kernel, dim3(CC), dim3(256), 0, stream,
                       weight, G, invnw, whi, wlo);
    hipLaunchKernelGGL(main_kernel, dim3(BB / 128, CC), dim3(128), 0, stream,
                       ehi, elo, whi, wlo, G, invnw, nemb, out);
}

// Round 5
// 109.613 us; speedup vs baseline: 8.3165x; 1.1134x over previous
//
#include <hip/hip_runtime.h>
#include <cstdint>
#include <cmath>

#define BB 1024
#define CC 256
#define SS 64
#define DD 128
#define TOPKN 8
#define EPSF 1e-8f

typedef __attribute__((ext_vector_type(8))) short short8;
typedef __attribute__((ext_vector_type(16))) float f32x16;

static __device__ __forceinline__ unsigned short f2bf(float x) {
    uint32_t u = __float_as_uint(x);
    uint32_t r = (u + 0x7FFFu + ((u >> 16) & 1u)) >> 16;   // RNE
    return (unsigned short)r;
}
static __device__ __forceinline__ float bf2f(unsigned short h) {
    return __uint_as_float(((uint32_t)h) << 16);
}

// ---- kernel A: split rows of a [R x 128] fp32 matrix into bf16 hi/lo
//      MFMA fragments + exact fp32 row norms / inverse norms. ----
// frag: hi[(tile*8+t)*64 + (kg&1)*32 + (r&31)] (short8), tile = r>>5, t = kg>>1
// (A-frag and B-frag of the 32x32x16 bf16 MFMA are byte-identical for this
//  indexing: lane ln holds M[ln&31][k=(ln>>5)*8+j] — validated by R4 pass.)
__global__ __launch_bounds__(256) void split_kernel(const float* __restrict__ src,
                                                    unsigned short* __restrict__ hi,
                                                    unsigned short* __restrict__ lo,
                                                    float* __restrict__ nrm,
                                                    float* __restrict__ invn) {
    int gid = blockIdx.x * 256 + threadIdx.x;   // 16 threads per row
    int r = gid >> 4, kg = gid & 15;
    const float4* srcp = (const float4*)(src + (size_t)r * DD + kg * 8);
    float4 v0 = srcp[0], v1 = srcp[1];
    float x[8] = {v0.x, v0.y, v0.z, v0.w, v1.x, v1.y, v1.z, v1.w};
    short8 h8, l8;
    float ss = 0.f;
    #pragma unroll
    for (int j = 0; j < 8; j++) {
        unsigned short h = f2bf(x[j]);
        h8[j] = (short)h;
        l8[j] = (short)f2bf(x[j] - bf2f(h));   // exact residual in fp32
        ss += x[j] * x[j];
    }
    size_t o = ((size_t)(r >> 5) * 8 + (kg >> 1)) * 64 + (kg & 1) * 32 + (r & 31);
    ((short8*)hi)[o] = h8;
    ((short8*)lo)[o] = l8;
    #pragma unroll
    for (int off = 8; off; off >>= 1) ss += __shfl_down(ss, off);
    if (kg == 0) {
        nrm[r] = sqrtf(ss);
        invn[r] = 1.0f / sqrtf(fmaxf(ss, 1e-30f));
    }
}

// ---- kernel B: G[c] = W[c] W[c]^T via bf16x3 MFMA (one wave per c) ----
// A-operand and B-operand use the SAME whi/wlo bytes (see split_kernel note).
__global__ __launch_bounds__(256) void gram_kernel(const unsigned short* __restrict__ whi,
                                                   const unsigned short* __restrict__ wlo,
                                                   float* __restrict__ G) {
    int lane = threadIdx.x & 63;
    int c = blockIdx.x * 4 + (threadIdx.x >> 6);
    const short8* Wh = (const short8*)whi;
    const short8* Wl = (const short8*)wlo;
    f32x16 acc[2][2] = {};
    for (int t = 0; t < 8; t++) {
        short8 wh[2], wl[2];
        #pragma unroll
        for (int i = 0; i < 2; i++) {
            size_t o = ((size_t)(c * 2 + i) * 8 + t) * 64 + lane;
            wh[i] = Wh[o]; wl[i] = Wl[o];
        }
        #pragma unroll
        for (int mi = 0; mi < 2; mi++)
            #pragma unroll
            for (int ni = 0; ni < 2; ni++) {
                acc[mi][ni] = __builtin_amdgcn_mfma_f32_32x32x16_bf16(wh[mi], wh[ni], acc[mi][ni], 0, 0, 0);
                acc[mi][ni] = __builtin_amdgcn_mfma_f32_32x32x16_bf16(wh[mi], wl[ni], acc[mi][ni], 0, 0, 0);
                acc[mi][ni] = __builtin_amdgcn_mfma_f32_32x32x16_bf16(wl[mi], wh[ni], acc[mi][ni], 0, 0, 0);
            }
    }
    // C/D layout: col=lane&31, row=(r&3)+8*(r>>2)+4*(lane>>5)  (validated R4)
    float* Gc = G + (size_t)c * SS * SS;
    #pragma unroll
    for (int mi = 0; mi < 2; mi++)
        #pragma unroll
        for (int ni = 0; ni < 2; ni++)
            #pragma unroll
            for (int r = 0; r < 16; r++) {
                int row = (r & 3) + 8 * (r >> 2) + 4 * (lane >> 5);
                Gc[(mi * 32 + row) * SS + ni * 32 + (lane & 31)] = acc[mi][ni][r];
            }
}

// ---- kernel C: fused MFMA dot (256 b x 64 s per block, one c) + epilogue ----
__global__ __launch_bounds__(256) void main_kernel(const unsigned short* __restrict__ ehi,
                                                   const unsigned short* __restrict__ elo,
                                                   const unsigned short* __restrict__ whi,
                                                   const unsigned short* __restrict__ wlo,
                                                   const float* __restrict__ G,
                                                   const float* __restrict__ invnw_g,
                                                   const float* __restrict__ nemb,
                                                   float* __restrict__ out) {
    // swizzled: value for (b_loc, s) lives at dotL[b_loc][(s + b_loc) & 63]
    // -> MFMA C-writes AND epilogue row-scans are both 2 lanes/bank (free)
    __shared__ float dotL[256][64];     // 64 KB -> 2 blocks/CU
    __shared__ float invnwL[SS];
    int tid = threadIdx.x, lane = tid & 63, w = tid >> 6;
    int c = blockIdx.y, b0 = blockIdx.x * 256;

    const short8* Ah = (const short8*)ehi;
    const short8* Al = (const short8*)elo;
    const short8* Bh = (const short8*)whi;
    const short8* Bl = (const short8*)wlo;
    int mbase = blockIdx.x * 8 + w * 2;
    f32x16 acc[2][2] = {};
    for (int t = 0; t < 8; t++) {
        short8 a_h[2], a_l[2], b_h[2], b_l[2];
        #pragma unroll
        for (int mi = 0; mi < 2; mi++) {
            size_t o = ((size_t)(mbase + mi) * 8 + t) * 64 + lane;
            a_h[mi] = Ah[o]; a_l[mi] = Al[o];
        }
        #pragma unroll
        for (int ni = 0; ni < 2; ni++) {
            size_t o = ((size_t)(c * 2 + ni) * 8 + t) * 64 + lane;
            b_h[ni] = Bh[o]; b_l[ni] = Bl[o];
        }
        #pragma unroll
        for (int mi = 0; mi < 2; mi++)
            #pragma unroll
            for (int ni = 0; ni < 2; ni++) {
                acc[mi][ni] = __builtin_amdgcn_mfma_f32_32x32x16_bf16(a_h[mi], b_h[ni], acc[mi][ni], 0, 0, 0);
                acc[mi][ni] = __builtin_amdgcn_mfma_f32_32x32x16_bf16(a_h[mi], b_l[ni], acc[mi][ni], 0, 0, 0);
                acc[mi][ni] = __builtin_amdgcn_mfma_f32_32x32x16_bf16(a_l[mi], b_h[ni], acc[mi][ni], 0, 0, 0);
            }
    }
    #pragma unroll
    for (int mi = 0; mi < 2; mi++)
        #pragma unroll
        for (int ni = 0; ni < 2; ni++)
            #pragma unroll
            for (int r = 0; r < 16; r++) {
                int row = (r & 3) + 8 * (r >> 2) + 4 * (lane >> 5);
                int bl = w * 64 + mi * 32 + row;
                int s = ni * 32 + (lane & 31);
                dotL[bl][(s + bl) & 63] = acc[mi][ni][r];
            }
    if (tid < SS) invnwL[tid] = invnw_g[c * SS + tid];
    __syncthreads();

    // ---------------- epilogue: 1 thread per b ----------------
    int bl = tid, b = b0 + tid;
    float ne = nemb[b];
    float inv_ne = 1.0f / ne;

    float ts[TOPKN]; int ti8[TOPKN];
    #pragma unroll
    for (int k = 0; k < TOPKN; k++) { ts[k] = -INFINITY; ti8[k] = 0; }
    #pragma unroll 8
    for (int s = 0; s < SS; s++) {
        float xs = dotL[bl][(s + bl) & 63] * invnwL[s];  // positive scale of cos
        int xi = s;
        #pragma unroll
        for (int k = 0; k < TOPKN; k++) {
            bool gt = xs > ts[k];              // strict: ties keep lower s
            float hs = gt ? xs : ts[k];  int hi = gt ? xi : ti8[k];
            float ls = gt ? ts[k] : xs;  int li = gt ? ti8[k] : xi;
            ts[k] = hs; ti8[k] = hi; xs = ls; xi = li;
        }
    }
    float sc[TOPKN];
    #pragma unroll
    for (int k = 0; k < TOPKN; k++) {
        float cosk = ts[k] * inv_ne;
        sc[k] = (1.0f + cosk) * 0.5f + EPSF;
    }
    float wk[TOPKN], wsum = 0.f;
    #pragma unroll
    for (int k = 0; k < TOPKN; k++) {
        float ev = expf(sc[k] - sc[0]);
        wk[k] = ev; wsum += ev;
    }
    float winv = 1.0f / wsum;

    float dot2 = 0.f;
    #pragma unroll
    for (int k = 0; k < TOPKN; k++) dot2 += wk[k] * dotL[bl][(ti8[k] + bl) & 63];

    // G gathers from global: G[c] is L2-resident (16 KB, c fixed per block)
    const float* Gc = G + (size_t)c * SS * SS;
    float Gd[TOPKN];
    #pragma unroll
    for (int k = 0; k < TOPKN; k++) Gd[k] = Gc[ti8[k] * SS + ti8[k]];
    float np2 = 0.f;
    #pragma unroll
    for (int j = 0; j < TOPKN; j++) {
        float wj = wk[j];
        np2 += wj * wj * Gd[j];
        #pragma unroll
        for (int k2 = j + 1; k2 < TOPKN; k2++)
            np2 += 2.0f * wj * wk[k2] * Gc[ti8[j] * SS + ti8[k2]];
    }
    dot2 *= winv;
    np2 *= winv * winv;

    float denom2 = fmaxf(sqrtf(fmaxf(np2, 0.f)) * ne, EPSF);
    float cos2 = dot2 / denom2;
    out[(size_t)b * CC + c] = ((1.0f + cos2) * 0.5f + EPSF) / 0.1f;
}

extern "C" void kernel_launch(void* const* d_in, const int* in_sizes, int n_in,
                              void* d_out, int out_size, void* d_ws, size_t ws_size,
                              hipStream_t stream) {
    const float* emb    = (const float*)d_in[0];
    const float* weight = (const float*)d_in[1];
    float* G      = (float*)d_ws;                                 // 4 MB
    float* invnw  = G + (size_t)CC * SS * SS;                     // 64 KB
    float* nw_scr = invnw + CC * SS;                              // 64 KB (scratch)
    float* nemb   = nw_scr + CC * SS;                             // 4 KB
    float* ine_scr= nemb + BB;                                    // 4 KB (scratch)
    unsigned short* ehi = (unsigned short*)(ine_scr + BB);        // 256 KB
    unsigned short* elo = ehi + (size_t)BB * DD;                  // 256 KB
    unsigned short* whi = elo + (size_t)BB * DD;                  // 4 MB
    unsigned short* wlo = whi + (size_t)CC * SS * DD;             // 4 MB
    float* out = (float*)d_out;

    hipLaunchKernelGGL(split_kernel, dim3(BB * 16 / 256), dim3(256), 0, stream,
                       emb, ehi, elo, nemb, ine_scr);
    hipLaunchKernelGGL(split_kernel, dim3(CC * SS * 16 / 256), dim3(256), 0, stream,
                       weight, whi, wlo, nw_scr, invnw);
    hipLaunchKernelGGL(gram_kernel, dim3(CC / 4), dim3(256), 0, stream,
                       whi, wlo, G);
    hipLaunchKernelGGL(main_kernel, dim3(BB / 256, CC), dim3(256), 0, stream,
                       ehi, elo, whi, wlo, G, invnw, nemb, out);
}

// Round 6
// 104.914 us; speedup vs baseline: 8.6890x; 1.0448x over previous
//
#include <hip/hip_runtime.h>
#include <cstdint>
#include <cmath>

#define BB 1024
#define CC 256
#define SS 64
#define DD 128
#define TOPKN 8
#define EPSF 1e-8f

typedef __attribute__((ext_vector_type(8))) short short8;
typedef __attribute__((ext_vector_type(16))) float f32x16;

static __device__ __forceinline__ unsigned short f2bf(float x) {
    uint32_t u = __float_as_uint(x);
    uint32_t r = (u + 0x7FFFu + ((u >> 16) & 1u)) >> 16;   // RNE
    return (unsigned short)r;
}
static __device__ __forceinline__ float bf2f(unsigned short h) {
    return __uint_as_float(((uint32_t)h) << 16);
}

// ---- kernel A: split emb (raw) and weight (pre-scaled by 1/||w||) into bf16
//      hi/lo MFMA fragments + norms. One launch covers both matrices.
// frag slot: hi[((r>>5)*8 + (kg>>1))*64 + (kg&1)*32 + (r&31)]  (short8)
// Weight rows are scaled by invnw in fp32 BEFORE splitting -> MFMA output is
// directly key = dot * invnw = cos * ne (ranking key; same 2^-18 noise class).
__global__ __launch_bounds__(256) void split_kernel(const float* __restrict__ emb,
                                                    const float* __restrict__ weight,
                                                    unsigned short* __restrict__ ehi,
                                                    unsigned short* __restrict__ elo,
                                                    unsigned short* __restrict__ whi,
                                                    unsigned short* __restrict__ wlo,
                                                    float* __restrict__ nemb,
                                                    float* __restrict__ nw_g) {
    int gid = blockIdx.x * 256 + threadIdx.x;   // 16 threads per row
    int row = gid >> 4, kg = gid & 15;
    bool isEmb = row < BB;                      // blocks never mix (1024 = 64*16)
    int r = isEmb ? row : row - BB;
    const float* src = isEmb ? emb : weight;
    const float4* sp = (const float4*)(src + (size_t)r * DD + kg * 8);
    float4 v0 = sp[0], v1 = sp[1];
    float x[8] = {v0.x, v0.y, v0.z, v0.w, v1.x, v1.y, v1.z, v1.w};
    float ss = 0.f;
    #pragma unroll
    for (int j = 0; j < 8; j++) ss += x[j] * x[j];
    #pragma unroll
    for (int off = 8; off; off >>= 1) ss += __shfl_xor(ss, off);  // all 16 lanes get total

    float scale;
    if (isEmb) {
        if (kg == 0) nemb[r] = sqrtf(ss);
        scale = 1.0f;
    } else {
        if (kg == 0) nw_g[r] = sqrtf(ss);
        scale = 1.0f / sqrtf(fmaxf(ss, 1e-30f));
    }
    short8 h8, l8;
    #pragma unroll
    for (int j = 0; j < 8; j++) {
        float xs = x[j] * scale;
        unsigned short h = f2bf(xs);
        h8[j] = (short)h;
        l8[j] = (short)f2bf(xs - bf2f(h));     // exact residual in fp32
    }
    size_t o = ((size_t)(r >> 5) * 8 + (kg >> 1)) * 64 + (kg & 1) * 32 + (r & 31);
    if (isEmb) { ((short8*)ehi)[o] = h8; ((short8*)elo)[o] = l8; }
    else       { ((short8*)whi)[o] = h8; ((short8*)wlo)[o] = l8; }
}

// ---- kernel B: G'[c] = Wn[c] Wn[c]^T via bf16x3 MFMA (Wn = row-normalized W) ----
__global__ __launch_bounds__(256) void gram_kernel(const unsigned short* __restrict__ whi,
                                                   const unsigned short* __restrict__ wlo,
                                                   float* __restrict__ G) {
    int lane = threadIdx.x & 63;
    int c = blockIdx.x * 4 + (threadIdx.x >> 6);
    const short8* Wh = (const short8*)whi;
    const short8* Wl = (const short8*)wlo;
    f32x16 acc[2][2] = {};
    for (int t = 0; t < 8; t++) {
        short8 wh[2], wl[2];
        #pragma unroll
        for (int i = 0; i < 2; i++) {
            size_t o = ((size_t)(c * 2 + i) * 8 + t) * 64 + lane;
            wh[i] = Wh[o]; wl[i] = Wl[o];
        }
        #pragma unroll
        for (int mi = 0; mi < 2; mi++)
            #pragma unroll
            for (int ni = 0; ni < 2; ni++) {
                acc[mi][ni] = __builtin_amdgcn_mfma_f32_32x32x16_bf16(wh[mi], wh[ni], acc[mi][ni], 0, 0, 0);
                acc[mi][ni] = __builtin_amdgcn_mfma_f32_32x32x16_bf16(wh[mi], wl[ni], acc[mi][ni], 0, 0, 0);
                acc[mi][ni] = __builtin_amdgcn_mfma_f32_32x32x16_bf16(wl[mi], wh[ni], acc[mi][ni], 0, 0, 0);
            }
    }
    float* Gc = G + (size_t)c * SS * SS;
    #pragma unroll
    for (int mi = 0; mi < 2; mi++)
        #pragma unroll
        for (int ni = 0; ni < 2; ni++)
            #pragma unroll
            for (int r = 0; r < 16; r++) {
                int row = (r & 3) + 8 * (r >> 2) + 4 * (lane >> 5);
                Gc[(mi * 32 + row) * SS + ni * 32 + (lane & 31)] = acc[mi][ni][r];
            }
}

// ---- kernel C: MFMA keys (256 b x 64 s, one c) + scores-only top-8 epilogue ----
__global__ __launch_bounds__(256) void main_kernel(const unsigned short* __restrict__ ehi,
                                                   const unsigned short* __restrict__ elo,
                                                   const unsigned short* __restrict__ whi,
                                                   const unsigned short* __restrict__ wlo,
                                                   const float* __restrict__ G,
                                                   const float* __restrict__ nw_g,
                                                   const float* __restrict__ nemb,
                                                   float* __restrict__ out) {
    // swizzled: (b_loc, s) lives at dotL[b_loc][(s + b_loc) & 63]
    // after the barrier, row t is private to thread t -> its first 16 floats
    // are reused as that thread's 8-slot (key, idx) queue (no extra LDS).
    __shared__ float dotL[256][64];     // 64 KB -> 2 blocks/CU
    int tid = threadIdx.x, lane = tid & 63, w = tid >> 6;
    int c = blockIdx.y, b0 = blockIdx.x * 256;

    const short8* Ah = (const short8*)ehi;
    const short8* Al = (const short8*)elo;
    const short8* Bh = (const short8*)whi;
    const short8* Bl = (const short8*)wlo;
    int mbase = blockIdx.x * 8 + w * 2;
    f32x16 acc[2][2] = {};
    #pragma unroll 2
    for (int t = 0; t < 8; t++) {
        short8 a_h[2], a_l[2], b_h[2], b_l[2];
        #pragma unroll
        for (int mi = 0; mi < 2; mi++) {
            size_t o = ((size_t)(mbase + mi) * 8 + t) * 64 + lane;
            a_h[mi] = Ah[o]; a_l[mi] = Al[o];
        }
        #pragma unroll
        for (int ni = 0; ni < 2; ni++) {
            size_t o = ((size_t)(c * 2 + ni) * 8 + t) * 64 + lane;
            b_h[ni] = Bh[o]; b_l[ni] = Bl[o];
        }
        #pragma unroll
        for (int mi = 0; mi < 2; mi++)
            #pragma unroll
            for (int ni = 0; ni < 2; ni++) {
                acc[mi][ni] = __builtin_amdgcn_mfma_f32_32x32x16_bf16(a_h[mi], b_h[ni], acc[mi][ni], 0, 0, 0);
                acc[mi][ni] = __builtin_amdgcn_mfma_f32_32x32x16_bf16(a_h[mi], b_l[ni], acc[mi][ni], 0, 0, 0);
                acc[mi][ni] = __builtin_amdgcn_mfma_f32_32x32x16_bf16(a_l[mi], b_h[ni], acc[mi][ni], 0, 0, 0);
            }
    }
    #pragma unroll
    for (int mi = 0; mi < 2; mi++)
        #pragma unroll
        for (int ni = 0; ni < 2; ni++)
            #pragma unroll
            for (int r = 0; r < 16; r++) {
                int row = (r & 3) + 8 * (r >> 2) + 4 * (lane >> 5);
                int bl = w * 64 + mi * 32 + row;
                int s = ni * 32 + (lane & 31);
                dotL[bl][(s + bl) & 63] = acc[mi][ni][r];
            }
    __syncthreads();

    // ---------------- epilogue: 1 thread per b ----------------
    int bl = tid, b = b0 + tid;
    float ne = nemb[b];
    float inv_ne = 1.0f / ne;

    // pass 0: keys (= cos * ne) into registers
    float key[SS];
    #pragma unroll
    for (int s = 0; s < SS; s++) key[s] = dotL[bl][(s + bl) & 63];

    // pass 1: top-8 VALUES only, sorted desc, via fmax/fmin bubbles (2 VALU/slot)
    float ts[TOPKN];
    #pragma unroll
    for (int k = 0; k < TOPKN; k++) ts[k] = -INFINITY;
    #pragma unroll
    for (int s = 0; s < SS; s++) {
        float x = key[s];
        #pragma unroll
        for (int k = 0; k < TOPKN; k++) {
            float hi = fmaxf(ts[k], x);
            x = fminf(ts[k], x);
            ts[k] = hi;
        }
    }
    float thresh = ts[7];

    // pass 2: recover (key, idx) — ascending s, >= thresh, first 8 = lax.top_k ties
    float* qp = &dotL[bl][0];           // overlays this thread's own dead row
    int cnt = 0;
    #pragma unroll
    for (int s = 0; s < SS; s++) {
        if (key[s] >= thresh && cnt < TOPKN) {
            qp[2 * cnt] = key[s];
            qp[2 * cnt + 1] = (float)s;
            cnt++;
        }
    }

    float kq[TOPKN]; int idx[TOPKN];
    #pragma unroll
    for (int k = 0; k < TOPKN; k++) {
        kq[k] = qp[2 * k];
        idx[k] = (int)qp[2 * k + 1];
    }

    // softmax over scores (max from ts[0]); order-invariant
    float sc0 = (1.0f + ts[0] * inv_ne) * 0.5f + EPSF;
    float wk[TOPKN], wsum = 0.f;
    #pragma unroll
    for (int k = 0; k < TOPKN; k++) {
        float sck = (1.0f + kq[k] * inv_ne) * 0.5f + EPSF;
        float ev = __expf(sck - sc0);
        wk[k] = ev; wsum += ev;
    }
    float winv = 1.0f / wsum;

    // v_k = w_k * nw_k ; dot2 = sum v_k key_k ; np2 = sum v_j v_k G'[j][k]
    const float* nwc = nw_g + c * SS;
    const float* Gc = G + (size_t)c * SS * SS;
    float vk[TOPKN];
    #pragma unroll
    for (int k = 0; k < TOPKN; k++) vk[k] = wk[k] * nwc[idx[k]];
    float dot2 = 0.f;
    #pragma unroll
    for (int k = 0; k < TOPKN; k++) dot2 += vk[k] * kq[k];
    float np2 = 0.f;
    #pragma unroll
    for (int j = 0; j < TOPKN; j++) {
        float vj = vk[j];
        np2 += vj * vj * Gc[idx[j] * SS + idx[j]];
        #pragma unroll
        for (int k2 = j + 1; k2 < TOPKN; k2++)
            np2 += 2.0f * vj * vk[k2] * Gc[idx[j] * SS + idx[k2]];
    }
    dot2 *= winv;
    np2 *= winv * winv;

    float denom2 = fmaxf(sqrtf(fmaxf(np2, 0.f)) * ne, EPSF);
    float cos2 = dot2 / denom2;
    out[(size_t)b * CC + c] = ((1.0f + cos2) * 0.5f + EPSF) / 0.1f;
}

extern "C" void kernel_launch(void* const* d_in, const int* in_sizes, int n_in,
                              void* d_out, int out_size, void* d_ws, size_t ws_size,
                              hipStream_t stream) {
    const float* emb    = (const float*)d_in[0];
    const float* weight = (const float*)d_in[1];
    float* G    = (float*)d_ws;                                   // 4 MB
    float* nw   = G + (size_t)CC * SS * SS;                       // 64 KB
    float* nemb = nw + CC * SS;                                   // 4 KB
    unsigned short* ehi = (unsigned short*)(nemb + BB);           // 256 KB
    unsigned short* elo = ehi + (size_t)BB * DD;                  // 256 KB
    unsigned short* whi = elo + (size_t)BB * DD;                  // 4 MB
    unsigned short* wlo = whi + (size_t)CC * SS * DD;             // 4 MB
    float* out = (float*)d_out;

    hipLaunchKernelGGL(split_kernel, dim3((BB + CC * SS) * 16 / 256), dim3(256), 0, stream,
                       emb, weight, ehi, elo, whi, wlo, nemb, nw);
    hipLaunchKernelGGL(gram_kernel, dim3(CC / 4), dim3(256), 0, stream,
                       whi, wlo, G);
    hipLaunchKernelGGL(main_kernel, dim3(BB / 256, CC), dim3(256), 0, stream,
                       ehi, elo, whi, wlo, G, nw, nemb, out);
}

// Round 7
// 102.443 us; speedup vs baseline: 8.8986x; 1.0241x over previous
//
#include <hip/hip_runtime.h>
#include <cstdint>
#include <cmath>

#define BB 1024
#define CC 256
#define SS 64
#define DD 128
#define TOPKN 8
#define EPSF 1e-8f

typedef __attribute__((ext_vector_type(8))) short short8;
typedef __attribute__((ext_vector_type(16))) float f32x16;

static __device__ __forceinline__ unsigned short f2bf(float x) {
    uint32_t u = __float_as_uint(x);
    uint32_t r = (u + 0x7FFFu + ((u >> 16) & 1u)) >> 16;   // RNE
    return (unsigned short)r;
}
static __device__ __forceinline__ float bf2f(unsigned short h) {
    return __uint_as_float(((uint32_t)h) << 16);
}

// ---- kernel A: split emb (raw) and weight (row-normalized) into bf16 hi/lo
//      MFMA fragments + norms. One launch covers both matrices. ----
__global__ __launch_bounds__(256) void split_kernel(const float* __restrict__ emb,
                                                    const float* __restrict__ weight,
                                                    unsigned short* __restrict__ ehi,
                                                    unsigned short* __restrict__ elo,
                                                    unsigned short* __restrict__ whi,
                                                    unsigned short* __restrict__ wlo,
                                                    float* __restrict__ nemb,
                                                    float* __restrict__ nw_g) {
    int gid = blockIdx.x * 256 + threadIdx.x;   // 16 threads per row
    int row = gid >> 4, kg = gid & 15;
    bool isEmb = row < BB;                      // blocks never mix (1024 = 64*16)
    int r = isEmb ? row : row - BB;
    const float* src = isEmb ? emb : weight;
    const float4* sp = (const float4*)(src + (size_t)r * DD + kg * 8);
    float4 v0 = sp[0], v1 = sp[1];
    float x[8] = {v0.x, v0.y, v0.z, v0.w, v1.x, v1.y, v1.z, v1.w};
    float ss = 0.f;
    #pragma unroll
    for (int j = 0; j < 8; j++) ss += x[j] * x[j];
    #pragma unroll
    for (int off = 8; off; off >>= 1) ss += __shfl_xor(ss, off);

    float scale;
    if (isEmb) {
        if (kg == 0) nemb[r] = sqrtf(ss);
        scale = 1.0f;
    } else {
        if (kg == 0) nw_g[r] = sqrtf(ss);
        scale = 1.0f / sqrtf(fmaxf(ss, 1e-30f));
    }
    short8 h8, l8;
    #pragma unroll
    for (int j = 0; j < 8; j++) {
        float xs = x[j] * scale;
        unsigned short h = f2bf(xs);
        h8[j] = (short)h;
        l8[j] = (short)f2bf(xs - bf2f(h));     // exact residual in fp32
    }
    size_t o = ((size_t)(r >> 5) * 8 + (kg >> 1)) * 64 + (kg & 1) * 32 + (r & 31);
    if (isEmb) { ((short8*)ehi)[o] = h8; ((short8*)elo)[o] = l8; }
    else       { ((short8*)whi)[o] = h8; ((short8*)wlo)[o] = l8; }
}

// ---- kernel B: H[c] = diag(nw) (Wn Wn^T) diag(nw)  (the unnormalized Gram),
//      via bf16x3 MFMA on normalized fragments. One wave per c. ----
__global__ __launch_bounds__(256) void gram_kernel(const unsigned short* __restrict__ whi,
                                                   const unsigned short* __restrict__ wlo,
                                                   const float* __restrict__ nw_g,
                                                   float* __restrict__ H) {
    int lane = threadIdx.x & 63;
    int c = blockIdx.x * 4 + (threadIdx.x >> 6);
    const short8* Wh = (const short8*)whi;
    const short8* Wl = (const short8*)wlo;
    f32x16 acc[2][2] = {};
    for (int t = 0; t < 8; t++) {
        short8 wh[2], wl[2];
        #pragma unroll
        for (int i = 0; i < 2; i++) {
            size_t o = ((size_t)(c * 2 + i) * 8 + t) * 64 + lane;
            wh[i] = Wh[o]; wl[i] = Wl[o];
        }
        #pragma unroll
        for (int mi = 0; mi < 2; mi++)
            #pragma unroll
            for (int ni = 0; ni < 2; ni++) {
                acc[mi][ni] = __builtin_amdgcn_mfma_f32_32x32x16_bf16(wh[mi], wh[ni], acc[mi][ni], 0, 0, 0);
                acc[mi][ni] = __builtin_amdgcn_mfma_f32_32x32x16_bf16(wh[mi], wl[ni], acc[mi][ni], 0, 0, 0);
                acc[mi][ni] = __builtin_amdgcn_mfma_f32_32x32x16_bf16(wl[mi], wh[ni], acc[mi][ni], 0, 0, 0);
            }
    }
    const float* nwc = nw_g + c * SS;
    float* Hc = H + (size_t)c * SS * SS;
    #pragma unroll
    for (int mi = 0; mi < 2; mi++)
        #pragma unroll
        for (int ni = 0; ni < 2; ni++) {
            float nwcol = nwc[ni * 32 + (lane & 31)];
            #pragma unroll
            for (int r = 0; r < 16; r++) {
                int row = (r & 3) + 8 * (r >> 2) + 4 * (lane >> 5);
                Hc[(mi * 32 + row) * SS + ni * 32 + (lane & 31)] =
                    acc[mi][ni][r] * nwc[mi * 32 + row] * nwcol;
            }
        }
}

// ---- kernel C: MFMA keys (256 b x 64 s, one c) + top-8 epilogue, zero
//      scattered global loads (H staged in LDS). ----
__global__ __launch_bounds__(256) void main_kernel(const unsigned short* __restrict__ ehi,
                                                   const unsigned short* __restrict__ elo,
                                                   const unsigned short* __restrict__ whi,
                                                   const unsigned short* __restrict__ wlo,
                                                   const float* __restrict__ H,
                                                   const float* __restrict__ nemb,
                                                   float* __restrict__ out) {
    // XOR swizzle: (bl, s) lives at dotL[bl][(s&3) | ((s>>2 ^ (bl>>2)&15)<<2)]
    // -> MFMA b32 writes <=2 lanes/bank; epilogue reads 16x ds_read_b128
    //    (4-lane broadcast groups, conflict-free).
    __shared__ float dotL[256][64];     // 64 KB
    __shared__ float Hs[SS * SS];       // 16 KB  (total 80 KB -> 2 blocks/CU)
    int tid = threadIdx.x, lane = tid & 63, w = tid >> 6;
    int c = blockIdx.y, b0 = blockIdx.x * 256;

    const short8* Ah = (const short8*)ehi;
    const short8* Al = (const short8*)elo;
    const short8* Bh = (const short8*)whi;
    const short8* Bl = (const short8*)wlo;
    int mbase = blockIdx.x * 8 + w * 2;
    f32x16 acc[2][2] = {};
    #pragma unroll 2
    for (int t = 0; t < 8; t++) {
        short8 a_h[2], a_l[2], b_h[2], b_l[2];
        #pragma unroll
        for (int mi = 0; mi < 2; mi++) {
            size_t o = ((size_t)(mbase + mi) * 8 + t) * 64 + lane;
            a_h[mi] = Ah[o]; a_l[mi] = Al[o];
        }
        #pragma unroll
        for (int ni = 0; ni < 2; ni++) {
            size_t o = ((size_t)(c * 2 + ni) * 8 + t) * 64 + lane;
            b_h[ni] = Bh[o]; b_l[ni] = Bl[o];
        }
        #pragma unroll
        for (int mi = 0; mi < 2; mi++)
            #pragma unroll
            for (int ni = 0; ni < 2; ni++) {
                acc[mi][ni] = __builtin_amdgcn_mfma_f32_32x32x16_bf16(a_h[mi], b_h[ni], acc[mi][ni], 0, 0, 0);
                acc[mi][ni] = __builtin_amdgcn_mfma_f32_32x32x16_bf16(a_h[mi], b_l[ni], acc[mi][ni], 0, 0, 0);
                acc[mi][ni] = __builtin_amdgcn_mfma_f32_32x32x16_bf16(a_l[mi], b_h[ni], acc[mi][ni], 0, 0, 0);
            }
    }
    #pragma unroll
    for (int mi = 0; mi < 2; mi++)
        #pragma unroll
        for (int ni = 0; ni < 2; ni++)
            #pragma unroll
            for (int r = 0; r < 16; r++) {
                int row = (r & 3) + 8 * (r >> 2) + 4 * (lane >> 5);
                int bl2 = w * 64 + mi * 32 + row;
                int s = ni * 32 + (lane & 31);
                int col = (s & 3) | ((((s >> 2) ^ ((bl2 >> 2) & 15))) << 2);
                dotL[bl2][col] = acc[mi][ni][r];
            }

    // stage H[c] (coalesced, 4 float4/thread)
    const float4* hsrc = (const float4*)(H + (size_t)c * SS * SS);
    #pragma unroll
    for (int j = 0; j < 4; j++)
        ((float4*)Hs)[j * 256 + tid] = hsrc[j * 256 + tid];
    __syncthreads();

    // ---------------- epilogue: 1 thread per b ----------------
    int bl = tid, b = b0 + tid;
    float ne = nemb[b];
    float inv_ne = 1.0f / ne;
    int xsw = (bl >> 2) & 15;

    // pass 0: keys (= cos * ne) via 16 ds_read_b128
    float key[SS];
    #pragma unroll
    for (int sg = 0; sg < 16; sg++) {
        float4 v = *(const float4*)&dotL[bl][(sg ^ xsw) << 2];
        key[sg * 4 + 0] = v.x; key[sg * 4 + 1] = v.y;
        key[sg * 4 + 2] = v.z; key[sg * 4 + 3] = v.w;
    }

    // pass 1: top-8 values only, sorted desc (fmax/fmin bubbles, 2 VALU/slot)
    float ts[TOPKN];
    #pragma unroll
    for (int k = 0; k < TOPKN; k++) ts[k] = -INFINITY;
    #pragma unroll
    for (int s = 0; s < SS; s++) {
        float x = key[s];
        #pragma unroll
        for (int k = 0; k < TOPKN; k++) {
            float hi = fmaxf(ts[k], x);
            x = fminf(ts[k], x);
            ts[k] = hi;
        }
    }
    float thresh = ts[7];

    // pass 2: recover (key, idx) — ascending s, first 8 = lax.top_k tie order
    float2* qp2 = (float2*)&dotL[bl][0];    // overlays this thread's dead row
    int cnt = 0;
    #pragma unroll
    for (int s = 0; s < SS; s++) {
        if (key[s] >= thresh && cnt < TOPKN) {
            qp2[cnt] = make_float2(key[s], (float)s);
            cnt++;
        }
    }
    float kq[TOPKN]; int idx[TOPKN];
    #pragma unroll
    for (int k = 0; k < TOPKN; k++) {
        float2 q = qp2[k];
        kq[k] = q.x;
        idx[k] = (int)q.y;
    }

    // softmax over scores (max = ts[0]); order-invariant
    float sc0 = (1.0f + ts[0] * inv_ne) * 0.5f + EPSF;
    float wk[TOPKN], wsum = 0.f;
    #pragma unroll
    for (int k = 0; k < TOPKN; k++) {
        float sck = (1.0f + kq[k] * inv_ne) * 0.5f + EPSF;
        float ev = __expf(sck - sc0);
        wk[k] = ev; wsum += ev;
    }
    float winv = 1.0f / wsum;

    // nw_k = sqrt(H[k][k]); dot2 = sum wk kq_k nw_k = p.e ; np2 = ||p||^2
    float Hd[TOPKN];
    #pragma unroll
    for (int k = 0; k < TOPKN; k++) Hd[k] = Hs[idx[k] * (SS + 1)];
    float dot2 = 0.f;
    #pragma unroll
    for (int k = 0; k < TOPKN; k++) dot2 += wk[k] * kq[k] * sqrtf(Hd[k]);
    float np2 = 0.f;
    #pragma unroll
    for (int j = 0; j < TOPKN; j++) {
        float wj = wk[j];
        np2 += wj * wj * Hd[j];
        #pragma unroll
        for (int k2 = j + 1; k2 < TOPKN; k2++)
            np2 += 2.0f * wj * wk[k2] * Hs[idx[j] * SS + idx[k2]];
    }
    dot2 *= winv;
    np2 *= winv * winv;

    float denom2 = fmaxf(sqrtf(fmaxf(np2, 0.f)) * ne, EPSF);
    float cos2 = dot2 / denom2;
    out[(size_t)b * CC + c] = ((1.0f + cos2) * 0.5f + EPSF) / 0.1f;
}

extern "C" void kernel_launch(void* const* d_in, const int* in_sizes, int n_in,
                              void* d_out, int out_size, void* d_ws, size_t ws_size,
                              hipStream_t stream) {
    const float* emb    = (const float*)d_in[0];
    const float* weight = (const float*)d_in[1];
    float* H    = (float*)d_ws;                                   // 4 MB
    float* nw   = H + (size_t)CC * SS * SS;                       // 64 KB
    float* nemb = nw + CC * SS;                                   // 4 KB
    unsigned short* ehi = (unsigned short*)(nemb + BB);           // 256 KB
    unsigned short* elo = ehi + (size_t)BB * DD;                  // 256 KB
    unsigned short* whi = elo + (size_t)BB * DD;                  // 4 MB
    unsigned short* wlo = whi + (size_t)CC * SS * DD;             // 4 MB
    float* out = (float*)d_out;

    hipLaunchKernelGGL(split_kernel, dim3((BB + CC * SS) * 16 / 256), dim3(256), 0, stream,
                       emb, weight, ehi, elo, whi, wlo, nemb, nw);
    hipLaunchKernelGGL(gram_kernel, dim3(CC / 4), dim3(256), 0, stream,
                       whi, wlo, nw, H);
    hipLaunchKernelGGL(main_kernel, dim3(BB / 256, CC), dim3(256), 0, stream,
                       ehi, elo, whi, wlo, H, nemb, out);
}

// Round 8
// 98.621 us; speedup vs baseline: 9.2434x; 1.0387x over previous
//
#include <hip/hip_runtime.h>
#include <cstdint>
#include <cmath>

#define BB 1024
#define CC 256
#define SS 64
#define DD 128
#define TOPKN 8
#define EPSF 1e-8f

typedef __attribute__((ext_vector_type(8))) short short8;
typedef __attribute__((ext_vector_type(16))) float f32x16;

static __device__ __forceinline__ unsigned short f2bf(float x) {
    uint32_t u = __float_as_uint(x);
    uint32_t r = (u + 0x7FFFu + ((u >> 16) & 1u)) >> 16;   // RNE
    return (unsigned short)r;
}
static __device__ __forceinline__ float bf2f(unsigned short h) {
    return __uint_as_float(((uint32_t)h) << 16);
}

// compare-exchange, descending (a keeps max)
#define CEX(a, b) { float _h = fmaxf(a, b), _l = fminf(a, b); (a) = _h; (b) = _l; }

// Batcher odd-even mergesort, 8 elems, descending. 19 comparators, depth 6.
static __device__ __forceinline__ void sort8(float* v) {
    CEX(v[0],v[1]); CEX(v[2],v[3]); CEX(v[4],v[5]); CEX(v[6],v[7]);
    CEX(v[0],v[2]); CEX(v[1],v[3]); CEX(v[4],v[6]); CEX(v[5],v[7]);
    CEX(v[1],v[2]); CEX(v[5],v[6]);
    CEX(v[0],v[4]); CEX(v[1],v[5]); CEX(v[2],v[6]); CEX(v[3],v[7]);
    CEX(v[2],v[4]); CEX(v[3],v[5]);
    CEX(v[1],v[2]); CEX(v[3],v[4]); CEX(v[5],v[6]);
}
// run := top-8 (sorted desc) of run ∪ cur; both inputs sorted desc.
// bitonic top-k: max(a[i], b[7-i]) holds the top-8 multiset, then 3 clean stages.
static __device__ __forceinline__ void merge8(float* run, const float* cur) {
    float t[8];
    #pragma unroll
    for (int i = 0; i < 8; i++) t[i] = fmaxf(run[i], cur[7 - i]);
    CEX(t[0],t[4]); CEX(t[1],t[5]); CEX(t[2],t[6]); CEX(t[3],t[7]);
    CEX(t[0],t[2]); CEX(t[1],t[3]); CEX(t[4],t[6]); CEX(t[5],t[7]);
    CEX(t[0],t[1]); CEX(t[2],t[3]); CEX(t[4],t[5]); CEX(t[6],t[7]);
    #pragma unroll
    for (int i = 0; i < 8; i++) run[i] = t[i];
}

// ---- kernel A: split emb (raw) and weight (row-normalized) into bf16 hi/lo
//      MFMA fragments + norms. (unchanged from R7 — proven) ----
__global__ __launch_bounds__(256) void split_kernel(const float* __restrict__ emb,
                                                    const float* __restrict__ weight,
                                                    unsigned short* __restrict__ ehi,
                                                    unsigned short* __restrict__ elo,
                                                    unsigned short* __restrict__ whi,
                                                    unsigned short* __restrict__ wlo,
                                                    float* __restrict__ nemb,
                                                    float* __restrict__ nw_g) {
    int gid = blockIdx.x * 256 + threadIdx.x;   // 16 threads per row
    int row = gid >> 4, kg = gid & 15;
    bool isEmb = row < BB;
    int r = isEmb ? row : row - BB;
    const float* src = isEmb ? emb : weight;
    const float4* sp = (const float4*)(src + (size_t)r * DD + kg * 8);
    float4 v0 = sp[0], v1 = sp[1];
    float x[8] = {v0.x, v0.y, v0.z, v0.w, v1.x, v1.y, v1.z, v1.w};
    float ss = 0.f;
    #pragma unroll
    for (int j = 0; j < 8; j++) ss += x[j] * x[j];
    #pragma unroll
    for (int off = 8; off; off >>= 1) ss += __shfl_xor(ss, off);

    float scale;
    if (isEmb) {
        if (kg == 0) nemb[r] = sqrtf(ss);
        scale = 1.0f;
    } else {
        if (kg == 0) nw_g[r] = sqrtf(ss);
        scale = 1.0f / sqrtf(fmaxf(ss, 1e-30f));
    }
    short8 h8, l8;
    #pragma unroll
    for (int j = 0; j < 8; j++) {
        float xs = x[j] * scale;
        unsigned short h = f2bf(xs);
        h8[j] = (short)h;
        l8[j] = (short)f2bf(xs - bf2f(h));
    }
    size_t o = ((size_t)(r >> 5) * 8 + (kg >> 1)) * 64 + (kg & 1) * 32 + (r & 31);
    if (isEmb) { ((short8*)ehi)[o] = h8; ((short8*)elo)[o] = l8; }
    else       { ((short8*)whi)[o] = h8; ((short8*)wlo)[o] = l8; }
}

// ---- kernel B: H[c] = diag(nw) (Wn Wn^T) diag(nw) via bf16x3 MFMA ----
__global__ __launch_bounds__(256) void gram_kernel(const unsigned short* __restrict__ whi,
                                                   const unsigned short* __restrict__ wlo,
                                                   const float* __restrict__ nw_g,
                                                   float* __restrict__ H) {
    int lane = threadIdx.x & 63;
    int c = blockIdx.x * 4 + (threadIdx.x >> 6);
    const short8* Wh = (const short8*)whi;
    const short8* Wl = (const short8*)wlo;
    f32x16 acc[2][2] = {};
    for (int t = 0; t < 8; t++) {
        short8 wh[2], wl[2];
        #pragma unroll
        for (int i = 0; i < 2; i++) {
            size_t o = ((size_t)(c * 2 + i) * 8 + t) * 64 + lane;
            wh[i] = Wh[o]; wl[i] = Wl[o];
        }
        #pragma unroll
        for (int mi = 0; mi < 2; mi++)
            #pragma unroll
            for (int ni = 0; ni < 2; ni++) {
                acc[mi][ni] = __builtin_amdgcn_mfma_f32_32x32x16_bf16(wh[mi], wh[ni], acc[mi][ni], 0, 0, 0);
                acc[mi][ni] = __builtin_amdgcn_mfma_f32_32x32x16_bf16(wh[mi], wl[ni], acc[mi][ni], 0, 0, 0);
                acc[mi][ni] = __builtin_amdgcn_mfma_f32_32x32x16_bf16(wl[mi], wh[ni], acc[mi][ni], 0, 0, 0);
            }
    }
    const float* nwc = nw_g + c * SS;
    float* Hc = H + (size_t)c * SS * SS;
    #pragma unroll
    for (int mi = 0; mi < 2; mi++)
        #pragma unroll
        for (int ni = 0; ni < 2; ni++) {
            float nwcol = nwc[ni * 32 + (lane & 31)];
            #pragma unroll
            for (int r = 0; r < 16; r++) {
                int row = (r & 3) + 8 * (r >> 2) + 4 * (lane >> 5);
                Hc[(mi * 32 + row) * SS + ni * 32 + (lane & 31)] =
                    acc[mi][ni][r] * nwc[mi * 32 + row] * nwcol;
            }
        }
}

// ---- kernel C: MFMA keys + top-8 epilogue. LDS 52 KB -> 3 blocks/CU. ----
__global__ __launch_bounds__(256, 3) void main_kernel(const unsigned short* __restrict__ ehi,
                                                      const unsigned short* __restrict__ elo,
                                                      const unsigned short* __restrict__ whi,
                                                      const unsigned short* __restrict__ wlo,
                                                      const float* __restrict__ H,
                                                      const float* __restrict__ nemb,
                                                      float* __restrict__ out) {
    // stride 36: row base 144B (16B-aligned for float4 reads); bank=(4*row+col)%32
    // -> MFMA b32 writes are 2 lanes/bank (free); reads are volume-bound.
    __shared__ float dotL[256][36];     // 36 KB, holds one 32-s half at a time
    __shared__ float Hs[SS * SS];       // 16 KB
    int tid = threadIdx.x, lane = tid & 63, w = tid >> 6;
    int c = blockIdx.y, b0 = blockIdx.x * 256;

    // issue Hs global loads early; LDS store after GEMM (overlaps MFMA)
    const float4* hsrc = (const float4*)(H + (size_t)c * SS * SS);
    float4 hreg[4];
    #pragma unroll
    for (int j = 0; j < 4; j++) hreg[j] = hsrc[j * 256 + tid];

    const short8* Ah = (const short8*)ehi;
    const short8* Al = (const short8*)elo;
    const short8* Bh = (const short8*)whi;
    const short8* Bl = (const short8*)wlo;
    int mbase = blockIdx.x * 8 + w * 2;
    f32x16 acc[2][2] = {};
    #pragma unroll 2
    for (int t = 0; t < 8; t++) {
        short8 a_h[2], a_l[2], b_h[2], b_l[2];
        #pragma unroll
        for (int mi = 0; mi < 2; mi++) {
            size_t o = ((size_t)(mbase + mi) * 8 + t) * 64 + lane;
            a_h[mi] = Ah[o]; a_l[mi] = Al[o];
        }
        #pragma unroll
        for (int ni = 0; ni < 2; ni++) {
            size_t o = ((size_t)(c * 2 + ni) * 8 + t) * 64 + lane;
            b_h[ni] = Bh[o]; b_l[ni] = Bl[o];
        }
        #pragma unroll
        for (int mi = 0; mi < 2; mi++)
            #pragma unroll
            for (int ni = 0; ni < 2; ni++) {
                acc[mi][ni] = __builtin_amdgcn_mfma_f32_32x32x16_bf16(a_h[mi], b_h[ni], acc[mi][ni], 0, 0, 0);
                acc[mi][ni] = __builtin_amdgcn_mfma_f32_32x32x16_bf16(a_h[mi], b_l[ni], acc[mi][ni], 0, 0, 0);
                acc[mi][ni] = __builtin_amdgcn_mfma_f32_32x32x16_bf16(a_l[mi], b_h[ni], acc[mi][ni], 0, 0, 0);
            }
    }
    #pragma unroll
    for (int j = 0; j < 4; j++) ((float4*)Hs)[j * 256 + tid] = hreg[j];

    // ---- key tile through LDS in two 32-s halves (keeps LDS at 36 KB) ----
    float key[SS];
    #pragma unroll
    for (int ni = 0; ni < 2; ni++) {
        #pragma unroll
        for (int mi = 0; mi < 2; mi++)
            #pragma unroll
            for (int r = 0; r < 16; r++) {
                int row = (r & 3) + 8 * (r >> 2) + 4 * (lane >> 5);
                dotL[w * 64 + mi * 32 + row][lane & 31] = acc[mi][ni][r];
            }
        __syncthreads();
        #pragma unroll
        for (int j = 0; j < 8; j++) {
            float4 v = *(const float4*)&dotL[tid][j * 4];
            key[ni * 32 + j * 4 + 0] = v.x; key[ni * 32 + j * 4 + 1] = v.y;
            key[ni * 32 + j * 4 + 2] = v.z; key[ni * 32 + j * 4 + 3] = v.w;
        }
        __syncthreads();
    }

    // ---------------- epilogue: 1 thread per b ----------------
    int b = b0 + tid;
    float ne = nemb[b];
    float inv_ne = 1.0f / ne;

    // exact top-8 VALUES via sorting networks (log-depth, ILP-friendly)
    float run[8], cur[8];
    #pragma unroll
    for (int i = 0; i < 8; i++) run[i] = key[i];
    sort8(run);
    #pragma unroll
    for (int g = 1; g < 8; g++) {
        #pragma unroll
        for (int i = 0; i < 8; i++) cur[i] = key[g * 8 + i];
        sort8(cur);
        merge8(run, cur);
    }
    float thresh = run[7];     // exact 8th largest

    // recover (key, idx): ascending s, first 8 >= thresh == lax.top_k tie set.
    // queue overlays this thread's own dotL row (private after last barrier).
    float2* qp2 = (float2*)&dotL[tid][0];
    int cnt = 0;
    #pragma unroll
    for (int s = 0; s < SS; s++) {
        if (key[s] >= thresh && cnt < TOPKN) {
            qp2[cnt] = make_float2(key[s], (float)s);
            cnt++;
        }
    }
    float kq[TOPKN]; int idx[TOPKN];
    #pragma unroll
    for (int k = 0; k < TOPKN; k++) {
        float2 q = qp2[k];
        kq[k] = q.x;
        idx[k] = (int)q.y;
    }

    // softmax over scores (max = run[0]); order-invariant pairing via idx
    float sc0 = (1.0f + run[0] * inv_ne) * 0.5f + EPSF;
    float wk[TOPKN], wsum = 0.f;
    #pragma unroll
    for (int k = 0; k < TOPKN; k++) {
        float sck = (1.0f + kq[k] * inv_ne) * 0.5f + EPSF;
        float ev = __expf(sck - sc0);
        wk[k] = ev; wsum += ev;
    }
    float winv = 1.0f / wsum;

    // nw_k = sqrt(H[k][k]); dot2 = p.e ; np2 = ||p||^2 (Gram bilinear form)
    float Hd[TOPKN];
    #pragma unroll
    for (int k = 0; k < TOPKN; k++) Hd[k] = Hs[idx[k] * (SS + 1)];
    float dot2 = 0.f;
    #pragma unroll
    for (int k = 0; k < TOPKN; k++) dot2 += wk[k] * kq[k] * sqrtf(Hd[k]);
    float np2 = 0.f;
    #pragma unroll
    for (int j = 0; j < TOPKN; j++) {
        float wj = wk[j];
        np2 += wj * wj * Hd[j];
        #pragma unroll
        for (int k2 = j + 1; k2 < TOPKN; k2++)
            np2 += 2.0f * wj * wk[k2] * Hs[idx[j] * SS + idx[k2]];
    }
    dot2 *= winv;
    np2 *= winv * winv;

    float denom2 = fmaxf(sqrtf(fmaxf(np2, 0.f)) * ne, EPSF);
    float cos2 = dot2 / denom2;
    out[(size_t)b * CC + c] = ((1.0f + cos2) * 0.5f + EPSF) / 0.1f;
}

extern "C" void kernel_launch(void* const* d_in, const int* in_sizes, int n_in,
                              void* d_out, int out_size, void* d_ws, size_t ws_size,
                              hipStream_t stream) {
    const float* emb    = (const float*)d_in[0];
    const float* weight = (const float*)d_in[1];
    float* H    = (float*)d_ws;                                   // 4 MB
    float* nw   = H + (size_t)CC * SS * SS;                       // 64 KB
    float* nemb = nw + CC * SS;                                   // 4 KB
    unsigned short* ehi = (unsigned short*)(nemb + BB);           // 256 KB
    unsigned short* elo = ehi + (size_t)BB * DD;                  // 256 KB
    unsigned short* whi = elo + (size_t)BB * DD;                  // 4 MB
    unsigned short* wlo = whi + (size_t)CC * SS * DD;             // 4 MB
    float* out = (float*)d_out;

    hipLaunchKernelGGL(split_kernel, dim3((BB + CC * SS) * 16 / 256), dim3(256), 0, stream,
                       emb, weight, ehi, elo, whi, wlo, nemb, nw);
    hipLaunchKernelGGL(gram_kernel, dim3(CC / 4), dim3(256), 0, stream,
                       whi, wlo, nw, H);
    hipLaunchKernelGGL(main_kernel, dim3(BB / 256, CC), dim3(256), 0, stream,
                       ehi, elo, whi, wlo, H, nemb, out);
}

// Round 9
// 91.983 us; speedup vs baseline: 9.9104x; 1.0722x over previous
//
#include <hip/hip_runtime.h>
#include <cstdint>
#include <cmath>

#define BB 1024
#define CC 256
#define SS 64
#define DD 128
#define TOPKN 8
#define EPSF 1e-8f

typedef __attribute__((ext_vector_type(8))) short short8;
typedef __attribute__((ext_vector_type(16))) float f32x16;

static __device__ __forceinline__ unsigned short f2bf(float x) {
    uint32_t u = __float_as_uint(x);
    uint32_t r = (u + 0x7FFFu + ((u >> 16) & 1u)) >> 16;   // RNE
    return (unsigned short)r;
}
static __device__ __forceinline__ float bf2f(unsigned short h) {
    return __uint_as_float(((uint32_t)h) << 16);
}

// compare-exchange, descending (a keeps max)
#define CEX(a, b) { float _h = fmaxf(a, b), _l = fminf(a, b); (a) = _h; (b) = _l; }

// Batcher odd-even mergesort, 8 elems, descending. 19 comparators, depth 6.
static __device__ __forceinline__ void sort8(float* v) {
    CEX(v[0],v[1]); CEX(v[2],v[3]); CEX(v[4],v[5]); CEX(v[6],v[7]);
    CEX(v[0],v[2]); CEX(v[1],v[3]); CEX(v[4],v[6]); CEX(v[5],v[7]);
    CEX(v[1],v[2]); CEX(v[5],v[6]);
    CEX(v[0],v[4]); CEX(v[1],v[5]); CEX(v[2],v[6]); CEX(v[3],v[7]);
    CEX(v[2],v[4]); CEX(v[3],v[5]);
    CEX(v[1],v[2]); CEX(v[3],v[4]); CEX(v[5],v[6]);
}
// run := top-8 (sorted desc) of run ∪ cur; both sorted desc (bitonic top-k).
static __device__ __forceinline__ void merge8(float* run, const float* cur) {
    float t[8];
    #pragma unroll
    for (int i = 0; i < 8; i++) t[i] = fmaxf(run[i], cur[7 - i]);
    CEX(t[0],t[4]); CEX(t[1],t[5]); CEX(t[2],t[6]); CEX(t[3],t[7]);
    CEX(t[0],t[2]); CEX(t[1],t[3]); CEX(t[4],t[6]); CEX(t[5],t[7]);
    CEX(t[0],t[1]); CEX(t[2],t[3]); CEX(t[4],t[5]); CEX(t[6],t[7]);
    #pragma unroll
    for (int i = 0; i < 8; i++) run[i] = t[i];
}

// ---- kernel A: split emb (raw) and weight (row-normalized) into bf16 hi/lo
//      MFMA fragments + exact fp32 norms. (proven since R6) ----
__global__ __launch_bounds__(256) void split_kernel(const float* __restrict__ emb,
                                                    const float* __restrict__ weight,
                                                    unsigned short* __restrict__ ehi,
                                                    unsigned short* __restrict__ elo,
                                                    unsigned short* __restrict__ whi,
                                                    unsigned short* __restrict__ wlo,
                                                    float* __restrict__ nemb,
                                                    float* __restrict__ nw_g) {
    int gid = blockIdx.x * 256 + threadIdx.x;   // 16 threads per row
    int row = gid >> 4, kg = gid & 15;
    bool isEmb = row < BB;
    int r = isEmb ? row : row - BB;
    const float* src = isEmb ? emb : weight;
    const float4* sp = (const float4*)(src + (size_t)r * DD + kg * 8);
    float4 v0 = sp[0], v1 = sp[1];
    float x[8] = {v0.x, v0.y, v0.z, v0.w, v1.x, v1.y, v1.z, v1.w};
    float ss = 0.f;
    #pragma unroll
    for (int j = 0; j < 8; j++) ss += x[j] * x[j];
    #pragma unroll
    for (int off = 8; off; off >>= 1) ss += __shfl_xor(ss, off);

    float scale;
    if (isEmb) {
        if (kg == 0) nemb[r] = sqrtf(ss);
        scale = 1.0f;
    } else {
        if (kg == 0) nw_g[r] = sqrtf(ss);
        scale = 1.0f / sqrtf(fmaxf(ss, 1e-30f));
    }
    short8 h8, l8;
    #pragma unroll
    for (int j = 0; j < 8; j++) {
        float xs = x[j] * scale;
        unsigned short h = f2bf(xs);
        h8[j] = (short)h;
        l8[j] = (short)f2bf(xs - bf2f(h));
    }
    size_t o = ((size_t)(r >> 5) * 8 + (kg >> 1)) * 64 + (kg & 1) * 32 + (r & 31);
    if (isEmb) { ((short8*)ehi)[o] = h8; ((short8*)elo)[o] = l8; }
    else       { ((short8*)whi)[o] = h8; ((short8*)wlo)[o] = l8; }
}

// ---- kernel B (fused): W->LDS staging, Gn quadrant MFMAs, key GEMM,
//      top-8 + proto epilogue. One block per (256-b group, c). ----
__global__ __launch_bounds__(256, 3) void main_kernel(const unsigned short* __restrict__ ehi,
                                                      const unsigned short* __restrict__ elo,
                                                      const unsigned short* __restrict__ whi,
                                                      const unsigned short* __restrict__ wlo,
                                                      const float* __restrict__ nw_g,
                                                      const float* __restrict__ nemb,
                                                      float* __restrict__ out) {
    // uni: first holds W[c] fragments (32 KB), then is reused as dotL[256][36]
    // (key staging) after the GEMM. Gs holds Gn = Wn Wn^T (cosine Gram).
    __shared__ __align__(16) float uni[256 * 36];   // 36 KB
    __shared__ float Gs[SS * SS];                   // 16 KB
    __shared__ float nwL[SS];
    short8* WsH = (short8*)uni;          // [ni(2)][t(8)][lane(64)] = 1024 short8
    short8* WsL = WsH + 1024;
    float (*dotL)[36] = (float(*)[36])uni;

    int tid = threadIdx.x, lane = tid & 63, w = tid >> 6;
    int c = blockIdx.y, b0 = blockIdx.x * 256;

    // ---- stage W[c] fragments (hi+lo, 32 KB) + nw[c] ----
    const short8* whg = (const short8*)whi + (size_t)c * 1024;
    const short8* wlg = (const short8*)wlo + (size_t)c * 1024;
    #pragma unroll
    for (int j = 0; j < 4; j++) {
        WsH[j * 256 + tid] = whg[j * 256 + tid];
        WsL[j * 256 + tid] = wlg[j * 256 + tid];
    }
    if (tid < SS) nwL[tid] = nw_g[c * SS + tid];
    __syncthreads();

    // ---- Gn quadrant (qi,qj) per wave: 24 MFMAs from LDS fragments ----
    {
        int qi = w & 1, qj = w >> 1;
        f32x16 gacc = {};
        #pragma unroll
        for (int t = 0; t < 8; t++) {
            short8 ah = WsH[(qi * 8 + t) * 64 + lane];
            short8 al = WsL[(qi * 8 + t) * 64 + lane];
            short8 bh = WsH[(qj * 8 + t) * 64 + lane];
            short8 bl = WsL[(qj * 8 + t) * 64 + lane];
            gacc = __builtin_amdgcn_mfma_f32_32x32x16_bf16(ah, bh, gacc, 0, 0, 0);
            gacc = __builtin_amdgcn_mfma_f32_32x32x16_bf16(ah, bl, gacc, 0, 0, 0);
            gacc = __builtin_amdgcn_mfma_f32_32x32x16_bf16(al, bh, gacc, 0, 0, 0);
        }
        #pragma unroll
        for (int r = 0; r < 16; r++) {
            int row = (r & 3) + 8 * (r >> 2) + 4 * (lane >> 5);
            Gs[(qi * 32 + row) * SS + qj * 32 + (lane & 31)] = gacc[r];
        }
    }

    // ---- key GEMM: emb frags from global, W frags from LDS ----
    const short8* Ah = (const short8*)ehi;
    const short8* Al = (const short8*)elo;
    int mbase = blockIdx.x * 8 + w * 2;
    f32x16 acc[2][2] = {};
    #pragma unroll 2
    for (int t = 0; t < 8; t++) {
        short8 a_h[2], a_l[2], b_h[2], b_l[2];
        #pragma unroll
        for (int mi = 0; mi < 2; mi++) {
            size_t o = ((size_t)(mbase + mi) * 8 + t) * 64 + lane;
            a_h[mi] = Ah[o]; a_l[mi] = Al[o];
        }
        #pragma unroll
        for (int ni = 0; ni < 2; ni++) {
            b_h[ni] = WsH[(ni * 8 + t) * 64 + lane];
            b_l[ni] = WsL[(ni * 8 + t) * 64 + lane];
        }
        #pragma unroll
        for (int mi = 0; mi < 2; mi++)
            #pragma unroll
            for (int ni = 0; ni < 2; ni++) {
                acc[mi][ni] = __builtin_amdgcn_mfma_f32_32x32x16_bf16(a_h[mi], b_h[ni], acc[mi][ni], 0, 0, 0);
                acc[mi][ni] = __builtin_amdgcn_mfma_f32_32x32x16_bf16(a_h[mi], b_l[ni], acc[mi][ni], 0, 0, 0);
                acc[mi][ni] = __builtin_amdgcn_mfma_f32_32x32x16_bf16(a_l[mi], b_h[ni], acc[mi][ni], 0, 0, 0);
            }
    }
    __syncthreads();   // all Ws reads done; Gs complete; uni may be reused

    // ---- key tile through LDS in two 32-s halves ----
    float key[SS];
    #pragma unroll
    for (int ni = 0; ni < 2; ni++) {
        #pragma unroll
        for (int mi = 0; mi < 2; mi++)
            #pragma unroll
            for (int r = 0; r < 16; r++) {
                int row = (r & 3) + 8 * (r >> 2) + 4 * (lane >> 5);
                dotL[w * 64 + mi * 32 + row][lane & 31] = acc[mi][ni][r];
            }
        __syncthreads();
        #pragma unroll
        for (int j = 0; j < 8; j++) {
            float4 v = *(const float4*)&dotL[tid][j * 4];
            key[ni * 32 + j * 4 + 0] = v.x; key[ni * 32 + j * 4 + 1] = v.y;
            key[ni * 32 + j * 4 + 2] = v.z; key[ni * 32 + j * 4 + 3] = v.w;
        }
        if (ni == 0) __syncthreads();   // rows reused by second half
    }

    // ---------------- epilogue: 1 thread per b ----------------
    int b = b0 + tid;
    float ne = nemb[b];
    float inv_ne = 1.0f / ne;

    // exact top-8 values via sorting networks
    float run[8], cur[8];
    #pragma unroll
    for (int i = 0; i < 8; i++) run[i] = key[i];
    sort8(run);
    #pragma unroll
    for (int g = 1; g < 8; g++) {
        #pragma unroll
        for (int i = 0; i < 8; i++) cur[i] = key[g * 8 + i];
        sort8(cur);
        merge8(run, cur);
    }
    float thresh = run[7];     // exact 8th largest

    // recover (key, idx): ascending s, first 8 >= thresh == lax.top_k tie set.
    // queue overlays this thread's OWN dotL row (row tid read only by thread tid).
    float2* qp2 = (float2*)&dotL[tid][0];
    int cnt = 0;
    #pragma unroll
    for (int s = 0; s < SS; s++) {
        if (key[s] >= thresh && cnt < TOPKN) {
            qp2[cnt] = make_float2(key[s], (float)s);
            cnt++;
        }
    }
    float kq[TOPKN]; int idx[TOPKN];
    #pragma unroll
    for (int k = 0; k < TOPKN; k++) {
        float2 q = qp2[k];
        kq[k] = q.x;
        idx[k] = (int)q.y;
    }

    // softmax over scores (max = run[0])
    float sc0 = (1.0f + run[0] * inv_ne) * 0.5f + EPSF;
    float wk[TOPKN], wsum = 0.f;
    #pragma unroll
    for (int k = 0; k < TOPKN; k++) {
        float sck = (1.0f + kq[k] * inv_ne) * 0.5f + EPSF;
        float ev = __expf(sck - sc0);
        wk[k] = ev; wsum += ev;
    }
    float winv = 1.0f / wsum;

    // v_k = w_k * nw_k (nw exact fp32); dot2 = p.e ; np2 = ||p||^2 via Gn
    float vk[TOPKN];
    #pragma unroll
    for (int k = 0; k < TOPKN; k++) vk[k] = wk[k] * nwL[idx[k]];
    float dot2 = 0.f;
    #pragma unroll
    for (int k = 0; k < TOPKN; k++) dot2 += vk[k] * kq[k];
    float np2 = 0.f;
    #pragma unroll
    for (int j = 0; j < TOPKN; j++) {
        float vj = vk[j];
        np2 += vj * vj * Gs[idx[j] * (SS + 1)];
        #pragma unroll
        for (int k2 = j + 1; k2 < TOPKN; k2++)
            np2 += 2.0f * vj * vk[k2] * Gs[idx[j] * SS + idx[k2]];
    }
    dot2 *= winv;
    np2 *= winv * winv;

    float denom2 = fmaxf(sqrtf(fmaxf(np2, 0.f)) * ne, EPSF);
    float cos2 = dot2 / denom2;
    out[(size_t)b * CC + c] = ((1.0f + cos2) * 0.5f + EPSF) / 0.1f;
}

extern "C" void kernel_launch(void* const* d_in, const int* in_sizes, int n_in,
                              void* d_out, int out_size, void* d_ws, size_t ws_size,
                              hipStream_t stream) {
    const float* emb    = (const float*)d_in[0];
    const float* weight = (const float*)d_in[1];
    float* nw   = (float*)d_ws;                                   // 64 KB
    float* nemb = nw + CC * SS;                                   // 4 KB
    unsigned short* ehi = (unsigned short*)(nemb + BB);           // 256 KB
    unsigned short* elo = ehi + (size_t)BB * DD;                  // 256 KB
    unsigned short* whi = elo + (size_t)BB * DD;                  // 4 MB
    unsigned short* wlo = whi + (size_t)CC * SS * DD;             // 4 MB
    float* out = (float*)d_out;

    hipLaunchKernelGGL(split_kernel, dim3((BB + CC * SS) * 16 / 256), dim3(256), 0, stream,
                       emb, weight, ehi, elo, whi, wlo, nemb, nw);
    hipLaunchKernelGGL(main_kernel, dim3(BB / 256, CC), dim3(256), 0, stream,
                       ehi, elo, whi, wlo, nw, nemb, out);
}